// Round 3
// baseline (566.191 us; speedup 1.0000x reference)
//
#include <hip/hip_runtime.h>
#include <hip/hip_bf16.h>

typedef short short8 __attribute__((ext_vector_type(8)));
typedef unsigned short ushortv8 __attribute__((ext_vector_type(8)));
typedef float floatx4 __attribute__((ext_vector_type(4)));

#define HP 168   // lH1 pitch (bf16): row stride 84 words = 20 mod 32 -> 2-way (free)

__device__ __forceinline__ unsigned short f2bf(float f) {
    __hip_bfloat16 h = __float2bfloat16(f);
    return __builtin_bit_cast(unsigned short, h);
}
__device__ __forceinline__ float bf2f(unsigned short s) {
    __hip_bfloat16 h = __builtin_bit_cast(__hip_bfloat16, s);
    return __bfloat162float(h);
}

// 16-lane row sum via v_add_f32_dpp row_ror — pure VALU, no LDS pipe.
__device__ __forceinline__ float dpp_sum16(float v) {
    v += __builtin_bit_cast(float, __builtin_amdgcn_update_dpp(
             0, __builtin_bit_cast(int, v), 0x128, 0xF, 0xF, true));  // row_ror:8
    v += __builtin_bit_cast(float, __builtin_amdgcn_update_dpp(
             0, __builtin_bit_cast(int, v), 0x124, 0xF, 0xF, true));  // row_ror:4
    v += __builtin_bit_cast(float, __builtin_amdgcn_update_dpp(
             0, __builtin_bit_cast(int, v), 0x122, 0xF, 0xF, true));  // row_ror:2
    v += __builtin_bit_cast(float, __builtin_amdgcn_update_dpp(
             0, __builtin_bit_cast(int, v), 0x121, 0xF, 0xF, true));  // row_ror:1
    return v;
}

// Pack Wc = [w1; wt] (320x320) into B-fragment order for mfma_f32_16x16x32_bf16.
// elem j of lane l for (t,kb): n = t*16+(l&15), k = kb*32+(l>>4)*8+j; flat (((t*10+kb)*64+l)*8+j)
__global__ void pack_wc(const float* __restrict__ w1, const float* __restrict__ wt,
                        unsigned short* __restrict__ dst) {
    int i = blockIdx.x * 256 + threadIdx.x;
    if (i >= 320 * 320) return;
    int j = i & 7;
    int lane = (i >> 3) & 63;
    int r = i >> 9;
    int kb = r % 10;
    int t = r / 10;
    int n = t * 16 + (lane & 15);
    int k = kb * 32 + ((lane >> 4) << 3) + j;
    float v = (n < 160) ? w1[n * 320 + k] : wt[(n - 160) * 320 + k];
    dst[i] = f2bf(v);
}

__global__ void pack_w2(const float* __restrict__ w2, unsigned short* __restrict__ dst) {
    int i = blockIdx.x * 256 + threadIdx.x;
    if (i >= 160 * 160) return;
    int j = i & 7;
    int lane = (i >> 3) & 63;
    int r = i >> 9;
    int kb = r % 5;
    int t = r / 5;
    int n = t * 16 + (lane & 15);
    int k = kb * 32 + ((lane >> 4) << 3) + j;
    dst[i] = f2bf(w2[n * 160 + k]);
}

// 32-row / 2-wave blocks. LDS = 20480 B -> 8 blocks/CU; launch_bounds(128,4) -> <=128 regs
// -> 16 waves/CU (vs 12 before), 8 independent blocks/CU for phase stagger.
// Wave 0: GEMM1 n[0,160) = h-half; wave 1: n[160,320) = ht-half (keeps ch[80,160) in regs).
__global__ __launch_bounds__(128, 4) void fused_kernel(
    const float* __restrict__ actors, const float* __restrict__ paths,
    const float* __restrict__ Z_act, const float* __restrict__ Z_pat,
    const int* __restrict__ u,
    const unsigned short* __restrict__ pB1, const unsigned short* __restrict__ pB2,
    const float* __restrict__ g1w, const float* __restrict__ g1b,
    const float* __restrict__ g2w, const float* __restrict__ g2b,
    const float* __restrict__ wh, const float* __restrict__ bh,
    float* __restrict__ out)
{
    // Phase 1: lX [0,20480) — X in MFMA A-fragment order:
    //   shorts addr = ((mt*10+kb)*64 + slot')*8, slot' = ((r&15)|(quad<<4)) ^ ((quad^kb)&7)
    // Phase 2 (aliases lX): lH1 [0,10752) 32xHP row-major; lHT [10752,15872) [80ch][8rg] ushort4;
    //   sP [15872,16384) [32]{s0,q0,s1,q1}; sDp [16384,16640) [32][2].
    __shared__ __align__(16) char smem[20480];
    unsigned short* lX  = (unsigned short*)smem;
    unsigned short* lH1 = (unsigned short*)smem;
    unsigned short* lHT = (unsigned short*)(smem + 10752);
    float* sP  = (float*)(smem + 15872);
    float* sDp = (float*)(smem + 16384);

    const int tid  = threadIdx.x;     // 0..127
    const int wave = tid >> 6;        // 0..1
    const int lane = tid & 63;
    const int quad = lane >> 4;
    const int l15  = lane & 15;
    const int row0 = blockIdx.x * 32;

    // ================= staging: 640 direct + 640 gather granules (8 k-elems each) ========
    // thread slot f = i*128+tid: r = f/20, q = f%20; handles direct (r,q8=q) and gather (r,q8=q+20)
    float4 vD[5][2], vG[5][2];
    int uv[5], rr[5], qq[5];
    #pragma unroll
    for (int i = 0; i < 5; i++) {     // direct loads + u loads (independent)
        int f = i * 128 + tid;
        int r = f / 20, q = f - r * 20;
        rr[i] = r; qq[i] = q;
        const float* src = (q < 16) ? (paths + (size_t)(row0 + r) * 128 + q * 8)
                                    : (Z_pat + (size_t)(row0 + r) * 32 + (q - 16) * 8);
        vD[i][0] = *(const float4*)src;
        vD[i][1] = *(const float4*)(src + 4);
        uv[i] = u[row0 + r];
    }
    #pragma unroll
    for (int i = 0; i < 5; i++) {     // dependent gather loads
        int q = qq[i];
        int un = uv[i];
        const float* src = (q < 16) ? (actors + (size_t)un * 128 + q * 8)
                                    : (Z_act + (size_t)un * 32 + (q - 16) * 8);
        vG[i][0] = *(const float4*)src;
        vG[i][1] = *(const float4*)(src + 4);
    }
    #pragma unroll
    for (int i = 0; i < 5; i++) {     // convert + fragment-order LDS write (b128)
        int r = rr[i], q = qq[i];
        int mt = r >> 4;
        {   // direct granule: k = q*8..q*8+7
            int kb = q >> 2, qd = q & 3;
            int slot = ((r & 15) | (qd << 4)) ^ ((qd ^ kb) & 7);
            ushortv8 sv;
            sv[0] = f2bf(vD[i][0].x); sv[1] = f2bf(vD[i][0].y);
            sv[2] = f2bf(vD[i][0].z); sv[3] = f2bf(vD[i][0].w);
            sv[4] = f2bf(vD[i][1].x); sv[5] = f2bf(vD[i][1].y);
            sv[6] = f2bf(vD[i][1].z); sv[7] = f2bf(vD[i][1].w);
            *(ushortv8*)(lX + ((mt * 10 + kb) * 64 + slot) * 8) = sv;
        }
        {   // gather granule: k = 160 + q*8..
            int q8 = q + 20;
            int kb = q8 >> 2, qd = q8 & 3;
            int slot = ((r & 15) | (qd << 4)) ^ ((qd ^ kb) & 7);
            ushortv8 sv;
            sv[0] = f2bf(vG[i][0].x); sv[1] = f2bf(vG[i][0].y);
            sv[2] = f2bf(vG[i][0].z); sv[3] = f2bf(vG[i][0].w);
            sv[4] = f2bf(vG[i][1].x); sv[5] = f2bf(vG[i][1].y);
            sv[6] = f2bf(vG[i][1].z); sv[7] = f2bf(vG[i][1].w);
            *(ushortv8*)(lX + ((mt * 10 + kb) * 64 + slot) * 8) = sv;
        }
    }

    // GEMM1 B ring prologue (depth 5, L2-resident pB1), independent of LDS
    const unsigned short* pBw = pB1 + (size_t)wave * 51200 + (size_t)lane * 8;
    short8 ring[5];
    #pragma unroll
    for (int p = 0; p < 5; p++) {     // p = kb*10+ti, p<5 -> kb=0, ti=p; rel shorts (ti*10+kb)*512
        ring[p] = *(const short8*)(pBw + (size_t)(p * 10) * 512);
    }
    __syncthreads();   // B1: lX ready

    // ================= GEMM1: C[32x320] = X @ [w1;wt]^T, n-half per wave =================
    floatx4 fzero = {0.f, 0.f, 0.f, 0.f};
    floatx4 acc[2][10];
    #pragma unroll
    for (int i = 0; i < 2; i++)
        #pragma unroll
        for (int j = 0; j < 10; j++) acc[i][j] = fzero;

    #pragma unroll
    for (int kb = 0; kb < 10; kb++) {
        int sl = (lane ^ ((quad ^ kb) & 7)) * 8;
        short8 a0 = *(const short8*)(lX + kb * 512 + sl);
        short8 a1 = *(const short8*)(lX + 5120 + kb * 512 + sl);
        #pragma unroll
        for (int ti = 0; ti < 10; ti++) {
            int p = kb * 10 + ti;
            short8 b = ring[p % 5];
            acc[0][ti] = __builtin_amdgcn_mfma_f32_16x16x32_bf16(a0, b, acc[0][ti], 0, 0, 0);
            acc[1][ti] = __builtin_amdgcn_mfma_f32_16x16x32_bf16(a1, b, acc[1][ti], 0, 0, 0);
            if (p + 5 < 100) {
                int p2 = p + 5, kb2 = p2 / 10, ti2 = p2 - kb2 * 10;
                ring[p2 % 5] = *(const short8*)(pBw + (size_t)(ti2 * 10 + kb2) * 512);
            }
        }
    }
    __syncthreads();   // B2: lX dead; lH1/lHT region live

    // ================= post-GEMM1: w0 = GN1 (wave-local stats) + lH1; w1 = ht ===========
    ushort4 hk[2][5];   // w1 keeps ht ch[80,160) packed over r
    if (wave == 0) {
        float mu_[2][4], rs_[2][4];
        #pragma unroll
        for (int mt = 0; mt < 2; mt++)
            #pragma unroll
            for (int r = 0; r < 4; r++) {
                float s = 0.f, q2 = 0.f;
                #pragma unroll
                for (int ti = 0; ti < 10; ti++) {
                    float v = acc[mt][ti][r];
                    s += v; q2 += v * v;
                }
                s = dpp_sum16(s); q2 = dpp_sum16(q2);
                float mu = s * (1.f / 160.f);
                float var = q2 * (1.f / 160.f) - mu * mu;
                mu_[mt][r] = mu;
                rs_[mt][r] = rsqrtf(var + 1e-5f);
            }
        float gw[10], gb[10];
        #pragma unroll
        for (int ti = 0; ti < 10; ti++) {
            int n = ti * 16 + l15;
            gw[ti] = g1w[n]; gb[ti] = g1b[n];
        }
        #pragma unroll
        for (int mt = 0; mt < 2; mt++)
            #pragma unroll
            for (int ti = 0; ti < 10; ti++)
                #pragma unroll
                for (int r = 0; r < 4; r++) {
                    float v = (acc[mt][ti][r] - mu_[mt][r]) * rs_[mt][r] * gw[ti] + gb[ti];
                    v = fmaxf(v, 0.f);
                    lH1[(mt * 16 + quad * 4 + r) * HP + ti * 16 + l15] = f2bf(v);
                }
    } else {
        #pragma unroll
        for (int mt = 0; mt < 2; mt++)
            #pragma unroll
            for (int tk = 0; tk < 5; tk++) {
                ushort4 kv;   // keep ch 80+tk*16+l15 (GEMM1 ti = tk+5)
                kv.x = f2bf(acc[mt][tk + 5][0]); kv.y = f2bf(acc[mt][tk + 5][1]);
                kv.z = f2bf(acc[mt][tk + 5][2]); kv.w = f2bf(acc[mt][tk + 5][3]);
                hk[mt][tk] = kv;
                ushort4 sv;   // store ch tk*16+l15 for wave 0
                sv.x = f2bf(acc[mt][tk][0]); sv.y = f2bf(acc[mt][tk][1]);
                sv.z = f2bf(acc[mt][tk][2]); sv.w = f2bf(acc[mt][tk][3]);
                int ch = tk * 16 + l15;
                int rg = (mt * 4 + quad) ^ (l15 & 7);
                *(ushort4*)(lHT + (ch * 8 + rg) * 4) = sv;
            }
    }

    // GEMM2 B ring prologue (independent of LDS)
    const unsigned short* pB2w = pB2 + (size_t)wave * 12800 + (size_t)lane * 8;
    short8 ring2[4];
    #pragma unroll
    for (int p = 0; p < 4; p++) {     // p = kb*5+ti, p<4 -> kb=0; rel shorts (ti*5+kb)*512
        ring2[p] = *(const short8*)(pB2w + (size_t)(p * 5) * 512);
    }
    __syncthreads();   // B3: lH1 + lHT ready

    // ================= GEMM2: h2[32x160] = h1 @ w2^T, ch-half per wave ===================
    floatx4 acc2[2][5];
    #pragma unroll
    for (int i = 0; i < 2; i++)
        #pragma unroll
        for (int j = 0; j < 5; j++) acc2[i][j] = fzero;

    #pragma unroll
    for (int kb = 0; kb < 5; kb++) {
        short8 a0 = *(const short8*)(lH1 + l15 * HP + kb * 32 + quad * 8);
        short8 a1 = *(const short8*)(lH1 + (16 + l15) * HP + kb * 32 + quad * 8);
        #pragma unroll
        for (int ti = 0; ti < 5; ti++) {
            int p = kb * 5 + ti;
            short8 b = ring2[p % 4];
            acc2[0][ti] = __builtin_amdgcn_mfma_f32_16x16x32_bf16(a0, b, acc2[0][ti], 0, 0, 0);
            acc2[1][ti] = __builtin_amdgcn_mfma_f32_16x16x32_bf16(a1, b, acc2[1][ti], 0, 0, 0);
            if (p + 4 < 25) {
                int p2 = p + 4, kb2 = p2 / 5, ti2 = p2 - kb2 * 5;
                ring2[p2 % 4] = *(const short8*)(pB2w + (size_t)(ti2 * 5 + kb2) * 512);
            }
        }
    }

    // ================= GN2 stats: per-wave partial (80 ch) -> LDS cross-wave ============
    #pragma unroll
    for (int mt = 0; mt < 2; mt++)
        #pragma unroll
        for (int r = 0; r < 4; r++) {
            float s = 0.f, q2 = 0.f;
            #pragma unroll
            for (int ti = 0; ti < 5; ti++) {
                float v = acc2[mt][ti][r];
                s += v; q2 += v * v;
            }
            s = dpp_sum16(s); q2 = dpp_sum16(q2);
            if (l15 == 0) {
                int m = mt * 16 + quad * 4 + r;
                float2 pv; pv.x = s; pv.y = q2;
                *(float2*)(sP + m * 4 + wave * 2) = pv;
            }
        }
    __syncthreads();   // B4: partials ready

    float mu2_[2][4], rs2_[2][4];
    #pragma unroll
    for (int mt = 0; mt < 2; mt++)
        #pragma unroll
        for (int r = 0; r < 4; r++) {
            int m = mt * 16 + quad * 4 + r;
            float4 pv = *(const float4*)(sP + m * 4);
            float ts = pv.x + pv.z;
            float tq = pv.y + pv.w;
            float mu = ts * (1.f / 160.f);
            float var = tq * (1.f / 160.f) - mu * mu;
            mu2_[mt][r] = mu;
            rs2_[mt][r] = rsqrtf(var + 1e-5f);
        }

    // ================= GN2 apply + skip(ht) + ReLU + head dot ===========================
    {
        float g2wv[5], g2bv[5], whv[5];
        #pragma unroll
        for (int ti = 0; ti < 5; ti++) {
            int n = wave * 80 + ti * 16 + l15;
            g2wv[ti] = g2w[n]; g2bv[ti] = g2b[n]; whv[ti] = wh[n];
        }
        float dp[8];
        #pragma unroll
        for (int k = 0; k < 8; k++) dp[k] = 0.f;

        #pragma unroll
        for (int mt = 0; mt < 2; mt++)
            #pragma unroll
            for (int ti = 0; ti < 5; ti++) {
                ushort4 hv;
                if (wave == 0) {
                    int ch = ti * 16 + l15;
                    int rg = (mt * 4 + quad) ^ (l15 & 7);
                    hv = *(const ushort4*)(lHT + (ch * 8 + rg) * 4);
                } else {
                    hv = hk[mt][ti];
                }
                float hvf[4];
                hvf[0] = bf2f(hv.x); hvf[1] = bf2f(hv.y);
                hvf[2] = bf2f(hv.z); hvf[3] = bf2f(hv.w);
                #pragma unroll
                for (int r = 0; r < 4; r++) {
                    float v = (acc2[mt][ti][r] - mu2_[mt][r]) * rs2_[mt][r] * g2wv[ti] + g2bv[ti];
                    v += hvf[r];
                    v = fmaxf(v, 0.f);
                    dp[mt * 4 + r] += v * whv[ti];
                }
            }
        #pragma unroll
        for (int k = 0; k < 8; k++) dp[k] = dpp_sum16(dp[k]);
        if (l15 == 0) {
            #pragma unroll
            for (int mt = 0; mt < 2; mt++)
                #pragma unroll
                for (int r = 0; r < 4; r++) {
                    int m = mt * 16 + quad * 4 + r;
                    sDp[m * 2 + wave] = dp[mt * 4 + r];
                }
        }
    }
    __syncthreads();   // B5: dp halves ready
    if (tid < 32) {
        float2 d = *(const float2*)(sDp + tid * 2);
        out[row0 + tid] = d.x + d.y + bh[0];
    }
}

extern "C" void kernel_launch(void* const* d_in, const int* in_sizes, int n_in,
                              void* d_out, int out_size, void* d_ws, size_t ws_size,
                              hipStream_t stream) {
    const float* actors = (const float*)d_in[0];
    const float* paths  = (const float*)d_in[1];
    const float* Z_act  = (const float*)d_in[2];
    const float* Z_pat  = (const float*)d_in[3];
    const int*   u      = (const int*)d_in[4];
    const float* w1     = (const float*)d_in[5];
    const float* w2     = (const float*)d_in[6];
    const float* wt     = (const float*)d_in[7];
    const float* g1w    = (const float*)d_in[8];
    const float* g1b    = (const float*)d_in[9];
    const float* g2w    = (const float*)d_in[10];
    const float* g2b    = (const float*)d_in[11];
    const float* wh     = (const float*)d_in[12];
    const float* bh     = (const float*)d_in[13];
    float* out = (float*)d_out;

    unsigned short* pB1 = (unsigned short*)d_ws;
    unsigned short* pB2 = pB1 + 320 * 320;

    hipLaunchKernelGGL(pack_wc, dim3(400), dim3(256), 0, stream, w1, wt, pB1);
    hipLaunchKernelGGL(pack_w2, dim3(100), dim3(256), 0, stream, w2, pB2);
    hipLaunchKernelGGL(fused_kernel, dim3(400000 / 32), dim3(128), 0, stream,
                       actors, paths, Z_act, Z_pat, u, pB1, pB2,
                       g1w, g1b, g2w, g2b, wh, bh, out);
}